// Round 10
// baseline (281.319 us; speedup 1.0000x reference)
//
#include <hip/hip_runtime.h>

#define T_TOK 2048
#define DIM   1024
#define FF    2048
#define NE    8
#define MAXTILES 40

typedef _Float16 f16x2 __attribute__((ext_vector_type(2)));
typedef _Float16 f16x4 __attribute__((ext_vector_type(4)));
typedef _Float16 f16x8 __attribute__((ext_vector_type(8)));
typedef float    f32x4 __attribute__((ext_vector_type(4)));

__device__ __forceinline__ f16x2 cvtpk(float a, float b) {
    return __builtin_bit_cast(f16x2, __builtin_amdgcn_cvt_pkrtz(a, b));
}
__device__ __forceinline__ void glds16(const void* g, void* l) {
    __builtin_amdgcn_global_load_lds(
        (const __attribute__((address_space(1))) unsigned int*)g,
        (__attribute__((address_space(3))) unsigned int*)l, 16, 0, 0);
}

// ---------------- router: logits/softmax/top2 + x->fp16 (NO atomics) ----------------
__global__ __launch_bounds__(256) void router_kernel(
    const float* __restrict__ x, const float* __restrict__ rw,
    float* __restrict__ gates_out, float* __restrict__ top1_out,
    int* __restrict__ e1a, int* __restrict__ e2a,
    float* __restrict__ g1a, float* __restrict__ g2a,
    _Float16* __restrict__ xh)
{
    const int wid  = threadIdx.x >> 6;
    const int lane = threadIdx.x & 63;
    const int t = blockIdx.x * 4 + wid;

    float acc[NE];
#pragma unroll
    for (int e = 0; e < NE; ++e) acc[e] = 0.f;

#pragma unroll
    for (int i = 0; i < 4; ++i) {
        const int d0 = i * 256 + lane * 4;
        f32x4 xv = *(const f32x4*)&x[(size_t)t * DIM + d0];
        f16x2 h0 = cvtpk(xv[0], xv[1]);
        f16x2 h1 = cvtpk(xv[2], xv[3]);
        f16x4 hv; hv[0] = h0[0]; hv[1] = h0[1]; hv[2] = h1[0]; hv[3] = h1[1];
        *(f16x4*)&xh[(size_t)t * DIM + d0] = hv;
#pragma unroll
        for (int j = 0; j < 4; ++j) {
            f32x4 wa = *(const f32x4*)&rw[(size_t)(d0 + j) * NE];
            f32x4 wb = *(const f32x4*)&rw[(size_t)(d0 + j) * NE + 4];
            float xs = xv[j];
            acc[0] += xs * wa[0]; acc[1] += xs * wa[1];
            acc[2] += xs * wa[2]; acc[3] += xs * wa[3];
            acc[4] += xs * wb[0]; acc[5] += xs * wb[1];
            acc[6] += xs * wb[2]; acc[7] += xs * wb[3];
        }
    }
#pragma unroll
    for (int off = 32; off > 0; off >>= 1) {
#pragma unroll
        for (int e = 0; e < NE; ++e)
            acc[e] += __shfl_xor(acc[e], off, 64);
    }

    float mx = acc[0];
#pragma unroll
    for (int e = 1; e < NE; ++e) mx = fmaxf(mx, acc[e]);
    float pr[NE]; float s = 0.f;
#pragma unroll
    for (int e = 0; e < NE; ++e) { pr[e] = expf(acc[e] - mx); s += pr[e]; }

    int e1 = 0; float b1v = acc[0];
#pragma unroll
    for (int e = 1; e < NE; ++e) if (acc[e] > b1v) { b1v = acc[e]; e1 = e; }
    int e2 = (e1 == 0) ? 1 : 0; float b2v = acc[e2];
#pragma unroll
    for (int e = 0; e < NE; ++e)
        if (e != e1 && acc[e] > b2v) { b2v = acc[e]; e2 = e; }

    float p1 = pr[e1] / s, p2 = pr[e2] / s;
    float denom = fmaxf(p1 + p2, 1.1920929e-07f);
    float gg1 = p1 / denom, gg2 = p2 / denom;

    if (lane < 8) gates_out[(size_t)t * NE + lane] = (lane == e1) ? gg1 : ((lane == e2) ? gg2 : 0.f);
    if (lane == 8)  top1_out[t] = (float)e1;
    if (lane == 9)  g1a[t] = gg1;
    if (lane == 10) g2a[t] = gg2;
    if (lane == 11) e1a[t] = e1;
    if (lane == 12) e2a[t] = e2;
}

// ---------------- compact: single block, ballot-based, no global atomics ----------------
__global__ __launch_bounds__(1024) void compact_kernel(
    const int* __restrict__ e1a, const int* __restrict__ e2a,
    int* __restrict__ cursor, int* __restrict__ atok, int* __restrict__ tslot)
{
    __shared__ int lbase[NE];
    __shared__ int woff[16][NE];
    const int tid = threadIdx.x, w = tid >> 6, lane = tid & 63;
    if (tid < NE) lbase[tid] = 0;
    __syncthreads();

    for (int b = 0; b < 4; ++b) {
        const int k = b * 1024 + tid;
        const int t = k >> 1;
        const int ex = (k & 1) ? e2a[t] : e1a[t];

        unsigned long long mymask = 0;
#pragma unroll
        for (int e = 0; e < NE; ++e) {
            unsigned long long m = __ballot(ex == e);
            if (ex == e) mymask = m;
            if (lane == e) woff[w][e] = __popcll(m);
        }
        const int rank = __popcll(mymask & ((1ull << lane) - 1));
        __syncthreads();

        if (tid < NE) {
            int s2 = lbase[tid];
            for (int ww = 0; ww < 16; ++ww) { int c = woff[ww][tid]; woff[ww][tid] = s2; s2 += c; }
            lbase[tid] = s2;
        }
        __syncthreads();

        const int slot = woff[w][ex] + rank;
        atok[ex * T_TOK + slot] = t;
        tslot[k] = (ex << 16) | slot;
        __syncthreads();
    }
    if (tid < NE) cursor[tid] = lbase[tid];
}

// ---------------- weight transpose+convert: W[E][K][N] f32 -> Wt[E][N][K] fp16 ----------------
template<int K, int N>
__global__ __launch_bounds__(256) void transp_kernel(
    const float* __restrict__ W, _Float16* __restrict__ Wt)
{
    const int n0 = blockIdx.x * 64, k0 = blockIdx.y * 64, e = blockIdx.z;
    __shared__ float Ts[64][65];
    const int tid = threadIdx.x;

    const float* src = W + ((size_t)e * K + k0) * N + n0;
#pragma unroll
    for (int i = 0; i < 4; ++i) {
        int row = (tid >> 4) + i * 16;
        int col = (tid & 15) * 4;
        f32x4 v = *(const f32x4*)&src[(size_t)row * N + col];
        *(f32x4*)&Ts[row][col] = v;
    }
    __syncthreads();

    const int n = tid >> 2, c0 = (tid & 3) * 16;
    f16x8 o0, o1;
#pragma unroll
    for (int j = 0; j < 8; ++j) o0[j] = (_Float16)Ts[c0 + j][n];
#pragma unroll
    for (int j = 0; j < 8; ++j) o1[j] = (_Float16)Ts[c0 + 8 + j][n];
    _Float16* dst = Wt + ((size_t)e * N + n0 + n) * K + k0 + c0;
    *(f16x8*)dst = o0;
    *(f16x8*)(dst + 8) = o1;
}

// ---------------- fc: all-glds grouped GEMM, 128x128 tile, counted vmcnt + T2 swizzle ----------------
// BM=128 BN=128 BK=64, 4 waves (2x2, wave tile 64x64), LDS dbuf 64KB, 2 blocks/CU
// Swizzle (rule 21): glds dest linear; SOURCE col-slot = (lane&7)^(lane>>3);
// reads XOR slot with (row&7).
template<bool IS_FC1>
__global__ __launch_bounds__(256, 2) void fc_kernel(
    const _Float16* __restrict__ Ag,
    const _Float16* __restrict__ Bt,
    const float* __restrict__ bias,
    const int* __restrict__ cnt, const int* __restrict__ atok,
    _Float16* __restrict__ Hout, _Float16* __restrict__ Yout)
{
    constexpr int K  = IS_FC1 ? DIM : FF;
    constexpr int N  = IS_FC1 ? FF : DIM;
    constexpr int KS = K / 64;

    int e = -1, m0 = 0, base = 0, ccur = 0, accT = 0;
#pragma unroll
    for (int i = 0; i < NE; ++i) {
        int c = cnt[i];
        int nt = (c + 127) >> 7;
        if (e < 0 && (int)blockIdx.y < accT + nt) { e = i; m0 = ((int)blockIdx.y - accT) * 128; ccur = c; }
        else if (e < 0) base += c;
        accT += nt;
    }
    if (e < 0) return;
    const int n0 = blockIdx.x * 128;

    __shared__ __align__(16) _Float16 As[2][128 * 64];
    __shared__ __align__(16) _Float16 Bs[2][128 * 64];

    const int tid = threadIdx.x, wid = tid >> 6, lane = tid & 63;
    const int wr = wid >> 1, wc = wid & 1;
    const int fr = lane & 15, fq = lane >> 4;

    // pre-swizzled source col slot (16B units) within each 128B k-row
    const int scol = ((lane & 7) ^ (lane >> 3)) * 16;

    const char* aptr[4];
#pragma unroll
    for (int i = 0; i < 4; ++i) {
        int row = wid * 32 + i * 8 + (lane >> 3);
        int rg = m0 + row; if (rg >= ccur) rg = ccur - 1;
        size_t srow = IS_FC1 ? (size_t)atok[e * T_TOK + rg] : (size_t)(base + rg);
        aptr[i] = (const char*)(Ag + srow * K) + scol;
    }
    const char* bptr[4];
#pragma unroll
    for (int j = 0; j < 4; ++j) {
        int row = wid * 32 + j * 8 + (lane >> 3);
        bptr[j] = (const char*)(Bt + ((size_t)e * N + n0 + row) * K) + scol;
    }

    f32x4 acc[4][4];
#pragma unroll
    for (int mi = 0; mi < 4; ++mi)
#pragma unroll
        for (int ni = 0; ni < 4; ++ni) acc[mi][ni] = (f32x4)0.0f;

    auto STAGE = [&](int buf, int kt) {
        const int kb = kt * 128;
#pragma unroll
        for (int i = 0; i < 4; ++i)
            glds16(aptr[i] + kb, &As[buf][(wid * 32 + i * 8) * 64]);
#pragma unroll
        for (int j = 0; j < 4; ++j)
            glds16(bptr[j] + kb, &Bs[buf][(wid * 32 + j * 8) * 64]);
    };
    auto COMPUTE = [&](int buf) {
#pragma unroll
        for (int kk = 0; kk < 2; ++kk) {
            f16x8 af[4], bf[4];
#pragma unroll
            for (int mi = 0; mi < 4; ++mi) {
                int row = wr * 64 + mi * 16 + fr;
                int slot = (kk * 4 + fq) ^ (fr & 7);
                af[mi] = *(const f16x8*)&As[buf][row * 64 + slot * 8];
            }
#pragma unroll
            for (int ni = 0; ni < 4; ++ni) {
                int row = wc * 64 + ni * 16 + fr;
                int slot = (kk * 4 + fq) ^ (fr & 7);
                bf[ni] = *(const f16x8*)&Bs[buf][row * 64 + slot * 8];
            }
#pragma unroll
            for (int mi = 0; mi < 4; ++mi)
#pragma unroll
                for (int ni = 0; ni < 4; ++ni)
                    acc[mi][ni] = __builtin_amdgcn_mfma_f32_16x16x32_f16(af[mi], bf[ni], acc[mi][ni], 0, 0, 0);
        }
    };

    STAGE(0, 0);

    for (int kt = 0; kt < KS; ++kt) {
        if (kt + 1 < KS) {
            STAGE((kt + 1) & 1, kt + 1);
            asm volatile("s_waitcnt vmcnt(8)" ::: "memory");   // stage(kt) landed; stage(kt+1)'s 8 in flight
        } else {
            asm volatile("s_waitcnt vmcnt(0)" ::: "memory");
        }
        __builtin_amdgcn_s_barrier();
        COMPUTE(kt & 1);
        asm volatile("s_waitcnt lgkmcnt(0)" ::: "memory");
        __builtin_amdgcn_s_barrier();
    }

    const int m_base = m0 + wr * 64 + fq * 4;
    const int n_base = n0 + wc * 64 + fr;
#pragma unroll
    for (int ni = 0; ni < 4; ++ni) {
        int n = n_base + ni * 16;
        float bv = bias[(size_t)e * N + n];
#pragma unroll
        for (int mi = 0; mi < 4; ++mi) {
#pragma unroll
            for (int r = 0; r < 4; ++r) {
                int m = m_base + mi * 16 + r;
                if (m < ccur) {
                    float v = acc[mi][ni][r] + bv;
                    if (IS_FC1)
                        Hout[(size_t)(base + m) * FF + n] = (_Float16)fmaxf(v, 0.f);
                    else
                        Yout[(size_t)(base + m) * DIM + n] = (_Float16)v;
                }
            }
        }
    }
}

// ---------------- combine: out = g1*y1 + g2*y2, where(==0, x) ----------------
__global__ __launch_bounds__(256) void combine_kernel(
    const float* __restrict__ x, const _Float16* __restrict__ Y,
    const int* __restrict__ tslot, const float* __restrict__ g1a,
    const float* __restrict__ g2a, const int* __restrict__ cnt,
    float* __restrict__ out)
{
    __shared__ int sbase[NE];
    if (threadIdx.x == 0) {
        int s = 0;
#pragma unroll
        for (int i = 0; i < NE; ++i) { sbase[i] = s; s += cnt[i]; }
    }
    __syncthreads();
    const int t = blockIdx.x;
    const int d = threadIdx.x * 4;
    int p1 = tslot[2 * t], p2 = tslot[2 * t + 1];
    int s1 = sbase[p1 >> 16] + (p1 & 0xffff);
    int s2 = sbase[p2 >> 16] + (p2 & 0xffff);
    const float a = g1a[t], b = g2a[t];
    f16x4 y1 = *(const f16x4*)&Y[(size_t)s1 * DIM + d];
    f16x4 y2 = *(const f16x4*)&Y[(size_t)s2 * DIM + d];
    f32x4 xv = *(const f32x4*)&x[(size_t)t * DIM + d];
    f32x4 o;
#pragma unroll
    for (int j = 0; j < 4; ++j) {
        float v = a * (float)y1[j] + b * (float)y2[j];
        o[j] = (v == 0.f) ? xv[j] : v;
    }
    *(f32x4*)&out[(size_t)t * DIM + d] = o;
}

extern "C" void kernel_launch(void* const* d_in, const int* in_sizes, int n_in,
                              void* d_out, int out_size, void* d_ws, size_t ws_size,
                              hipStream_t stream) {
    (void)in_sizes; (void)n_in; (void)out_size; (void)ws_size;
    const float* x  = (const float*)d_in[0];
    const float* rw = (const float*)d_in[1];
    const float* w1 = (const float*)d_in[2];
    const float* b1 = (const float*)d_in[3];
    const float* w2 = (const float*)d_in[4];
    const float* b2 = (const float*)d_in[5];

    float* out       = (float*)d_out;
    float* gates_out = out + (size_t)T_TOK * DIM;
    float* top1_out  = gates_out + (size_t)T_TOK * NE;

    char* ws = (char*)d_ws;
    int*   cursor = (int*)ws;
    int*   atok   = (int*)(ws + 4096);
    int*   tslot  = (int*)(ws + 69632);
    float* g1a    = (float*)(ws + 86016);
    float* g2a    = (float*)(ws + 94208);
    int*   e1a    = (int*)(ws + 102400);
    int*   e2a    = (int*)(ws + 110592);
    _Float16* xh  = (_Float16*)(ws + 131072);                               // 4MB
    _Float16* H   = (_Float16*)(ws + 131072 + (size_t)4 * 1024 * 1024);     // 16MB
    _Float16* Yh  = (_Float16*)(ws + 131072 + (size_t)20 * 1024 * 1024);    // 8MB
    _Float16* wt  = (_Float16*)(ws + 131072 + (size_t)28 * 1024 * 1024);    // 32MB (w1t, then w2t)

    router_kernel<<<T_TOK / 4, 256, 0, stream>>>(x, rw, gates_out, top1_out,
                                                 e1a, e2a, g1a, g2a, xh);
    transp_kernel<DIM, FF><<<dim3(FF / 64, DIM / 64, NE), 256, 0, stream>>>(w1, wt);
    compact_kernel<<<1, 1024, 0, stream>>>(e1a, e2a, cursor, atok, tslot);
    fc_kernel<true><<<dim3(FF / 128, MAXTILES), 256, 0, stream>>>(xh, wt, b1, cursor, atok, H, Yh);
    transp_kernel<FF, DIM><<<dim3(DIM / 64, FF / 64, NE), 256, 0, stream>>>(w2, wt);
    fc_kernel<false><<<dim3(DIM / 128, MAXTILES), 256, 0, stream>>>(H, wt, b2, cursor, atok, H, Yh);
    combine_kernel<<<T_TOK, 256, 0, stream>>>(x, Yh, tslot, g1a, g2a, cursor, out);
}